// Round 9
// baseline (176.626 us; speedup 1.0000x reference)
//
#include <hip/hip_runtime.h>
#include <math.h>

#define CIN 3
#define DIN 16
#define HIN 128
#define WIN 128
#define COUT 24
#define HOUT 126
#define DOUT 14
#define HW (HIN * WIN)

using f16x8 = __attribute__((ext_vector_type(8))) _Float16;
using f32x4 = __attribute__((ext_vector_type(4))) float;

// Row-order im2col (R7 layout, proven): 162 rows x 16 px, row stride 18 halves
// so 4 kg-group column-gathers spread banks (measured 0 conflicts in R7).
#define ROWSTRIDE 18
#define SLOT_HALVES (162 * ROWSTRIDE)            // 2916
#define TAIL 96                                   // overread zone (rows 162..166 of slot 1)
#define LDS_HALVES (2 * SLOT_HALVES + TAIL)

// R9: register-cached A-fragments. Each depth slice is gathered from LDS ONCE
// (32 ds_read_u16/thread) into A2; A0/A1 shift by register moves. 2-slot LDS
// ring (slice dp+2 lives in slot dp%2). One barrier per dp.
__global__ __launch_bounds__(256, 3) void conv3d_min_softmax_mfma(
    const float* __restrict__ x,
    const float* __restrict__ wgt,
    const float* __restrict__ bias,
    float* __restrict__ out)
{
    __shared__ _Float16 imX[LDS_HALVES];

    const int tid  = threadIdx.x;
    const int wv   = tid >> 6;
    const int lane = tid & 63;
    const int cl   = lane & 15;   // A: px-lane | B/C: co-lane
    const int kg   = lane >> 4;   // A/B: k-group | C: px-row-group

    const int wchunk = blockIdx.x;
    const int band   = blockIdx.y;
    const int b      = blockIdx.z;
    const int w0 = (wchunk < 7) ? wchunk * 16 : 110;   // overlap chunk: identical math, benign
    const int h0 = (band   < 7) ? band   * 16 : 110;

    const float* xb = x + (size_t)b * (CIN * DIN * HW);

    // zero the static tail: slot-1 overreads (k>=27) must see finite data, never NaN
    for (int i = 2 * SLOT_HALVES + tid; i < LDS_HALVES; i += 256)
        imX[i] = (_Float16)0.f;

    // ---- B-fragments (weights) in regs; k-order = kh*9 + ci*3 + kw; pads -> 0
    f16x8 bw[3][2];   // [kd][co-half]
    #pragma unroll
    for (int kd = 0; kd < 3; ++kd)
      #pragma unroll
      for (int hf = 0; hf < 2; ++hf)
        #pragma unroll
        for (int j = 0; j < 8; ++j) {
          int k  = kg * 8 + j;
          int co = hf * 16 + cl;
          float wvv = 0.f;
          if (k < 27 && co < 24) {
            int kh = k / 9, rem = k - kh * 9, ci = rem / 3, kw = rem - ci * 3;
            wvv = wgt[((co * 3 + ci) * 3 + kd) * 9 + kh * 3 + kw];
          }
          bw[kd][hf][j] = (_Float16)wvv;
        }

    const float bias0 = bias[cl];
    const float bias1 = (cl < 8) ? bias[16 + cl] : 0.f;

    // ---- builder offsets (R7, proven): thread handles elems e = tid + it*256
    int goff[11];   // global offset within a slice
    int lidx[11];   // LDS index within a slot
    int eidx[11];
    #pragma unroll
    for (int it = 0; it < 11; ++it) {
      int e = tid + it * 256;
      eidx[it] = e;
      int ec = (e < 2592) ? e : 0;
      int hrow = ec / 144, e2 = ec - hrow * 144;
      int ci   = e2 / 48,  e3 = e2 - ci * 48;
      int kw   = e3 >> 4,  px = e3 & 15;
      goff[it] = (ci * DIN) * HW + (h0 + hrow) * WIN + (w0 + kw + px);
      lidx[it] = (hrow * 9 + ci * 3 + kw) * ROWSTRIDE + px;
    }

    // per-tile gather row bases (column cl of rows 9*rel_h+8*kg ..+7)
    int rbase[4];
    #pragma unroll
    for (int t = 0; t < 4; ++t)
      rbase[t] = ((wv * 4 + t) * 9 + kg * 8) * ROWSTRIDE + cl;

    // ---- prologue: build slices 0,1; gather A0,A1; build slice 2; gather A2
    #pragma unroll 1
    for (int s = 0; s < 2; ++s) {
      #pragma unroll
      for (int it = 0; it < 11; ++it)
        if (eidx[it] < 2592)
          imX[s * SLOT_HALVES + lidx[it]] = (_Float16)xb[goff[it] + s * HW];
    }
    __syncthreads();

    f16x8 A0[4], A1[4], A2[4];
    #pragma unroll
    for (int t = 0; t < 4; ++t)
      #pragma unroll
      for (int j = 0; j < 8; ++j) {
        A0[t][j] = imX[0 * SLOT_HALVES + rbase[t] + j * ROWSTRIDE];
        A1[t][j] = imX[1 * SLOT_HALVES + rbase[t] + j * ROWSTRIDE];
      }
    __syncthreads();   // gathers of slot 0 done before slice-2 overwrite

    #pragma unroll
    for (int it = 0; it < 11; ++it)
      if (eidx[it] < 2592)
        imX[0 * SLOT_HALVES + lidx[it]] = (_Float16)xb[goff[it] + 2 * HW];
    __syncthreads();

    #pragma unroll
    for (int t = 0; t < 4; ++t)
      #pragma unroll
      for (int j = 0; j < 8; ++j)
        A2[t][j] = imX[0 * SLOT_HALVES + rbase[t] + j * ROWSTRIDE];

    // ---- main dp loop. Invariant entering dp: A0/A1/A2 = slices dp,dp+1,dp+2;
    // slot (dp+1)%2 holds slice dp+1 (disposable), slot dp%2 holds slice dp+2.
    float mn[4][2][4];
    #pragma unroll
    for (int t = 0; t < 4; ++t)
      #pragma unroll
      for (int hf = 0; hf < 2; ++hf)
        #pragma unroll
        for (int j = 0; j < 4; ++j) mn[t][hf][j] = 3.4e38f;

    #pragma unroll 1
    for (int dp = 0; dp < DOUT; ++dp) {
      const bool more = (dp < DOUT - 1);         // slice dp+3 <= 15 exists iff dp<13

      // 1) issue next-slice global loads early (hidden under MFMA)
      float stash[11];
      if (more) {
        #pragma unroll
        for (int it = 0; it < 11; ++it)
          if (eidx[it] < 2592)
            stash[it] = xb[goff[it] + (dp + 3) * HW];
      }

      // 2) compute from registers: 4 tiles x (3 kd chained) x 2 co-halves
      #pragma unroll
      for (int t = 0; t < 4; ++t) {
        f32x4 z = {0.f, 0.f, 0.f, 0.f};
        f32x4 acc0 = __builtin_amdgcn_mfma_f32_16x16x32_f16(A0[t], bw[0][0], z, 0, 0, 0);
        f32x4 acc1 = __builtin_amdgcn_mfma_f32_16x16x32_f16(A0[t], bw[0][1], z, 0, 0, 0);
        acc0 = __builtin_amdgcn_mfma_f32_16x16x32_f16(A1[t], bw[1][0], acc0, 0, 0, 0);
        acc1 = __builtin_amdgcn_mfma_f32_16x16x32_f16(A1[t], bw[1][1], acc1, 0, 0, 0);
        acc0 = __builtin_amdgcn_mfma_f32_16x16x32_f16(A2[t], bw[2][0], acc0, 0, 0, 0);
        acc1 = __builtin_amdgcn_mfma_f32_16x16x32_f16(A2[t], bw[2][1], acc1, 0, 0, 0);
        #pragma unroll
        for (int j = 0; j < 4; ++j) {
          mn[t][0][j] = fminf(mn[t][0][j], acc0[j]);
          mn[t][1][j] = fminf(mn[t][1][j], acc1[j]);
        }
      }

      if (more) {
        // 3) write slice dp+3 into slot (dp+1)%2 (slice dp+1's LDS copy is dead)
        const int sb = ((dp + 1) & 1) * SLOT_HALVES;
        #pragma unroll
        for (int it = 0; it < 11; ++it)
          if (eidx[it] < 2592)
            imX[sb + lidx[it]] = (_Float16)stash[it];
        // 4) barrier, then 5) shift regs + gather slice dp+3 once
        __syncthreads();
        #pragma unroll
        for (int t = 0; t < 4; ++t) { A0[t] = A1[t]; A1[t] = A2[t]; }
        #pragma unroll
        for (int t = 0; t < 4; ++t)
          #pragma unroll
          for (int j = 0; j < 8; ++j)
            A2[t][j] = imX[sb + rbase[t] + j * ROWSTRIDE];
      }
    }

    // ---- fused bias + softmax over channels (cross-lane over 16-lane group)
    float* ob = out + (size_t)b * COUT * HOUT * HOUT;
    #pragma unroll
    for (int t = 0; t < 4; ++t) {
      const int h = h0 + wv * 4 + t;
      #pragma unroll
      for (int j = 0; j < 4; ++j) {
        float v0 = mn[t][0][j] + bias0;
        float v1 = (cl < 8) ? (mn[t][1][j] + bias1) : -3.4e38f;
        float mx = fmaxf(v0, v1);
        #pragma unroll
        for (int msk = 1; msk < 16; msk <<= 1)
          mx = fmaxf(mx, __shfl_xor(mx, msk));
        float e0 = __expf(v0 - mx);
        float e1 = (cl < 8) ? __expf(v1 - mx) : 0.f;
        float sm = e0 + e1;
        #pragma unroll
        for (int msk = 1; msk < 16; msk <<= 1)
          sm += __shfl_xor(sm, msk);
        float r = 1.f / sm;
        const int w = w0 + kg * 4 + j;
        ob[((size_t)cl * HOUT + h) * HOUT + w] = e0 * r;
        if (cl < 8)
          ob[((size_t)(16 + cl) * HOUT + h) * HOUT + w] = e1 * r;
      }
    }
}

extern "C" void kernel_launch(void* const* d_in, const int* in_sizes, int n_in,
                              void* d_out, int out_size, void* d_ws, size_t ws_size,
                              hipStream_t stream) {
    const float* x    = (const float*)d_in[0];
    const float* wgt  = (const float*)d_in[1];
    const float* bias = (const float*)d_in[2];
    float* out        = (float*)d_out;

    dim3 grid(8, 8, 16);   // (wchunk, band, b)
    dim3 block(256);
    conv3d_min_softmax_mfma<<<grid, block, 0, stream>>>(x, wgt, bias, out);
}

// Round 10
// 84.328 us; speedup vs baseline: 2.0945x; 2.0945x over previous
//
#include <hip/hip_runtime.h>
#include <math.h>

#define CIN 3
#define DIN 16
#define HIN 128
#define WIN 128
#define COUT 24
#define HOUT 126
#define DOUT 14
#define HW (HIN * WIN)

using f16x8 = __attribute__((ext_vector_type(8))) _Float16;
using f32x4 = __attribute__((ext_vector_type(4))) float;

// Row-order im2col (R7 layout, proven): 162 rows x 16 px, row stride 18 halves
// so 4 kg-group column-gathers spread banks (measured 0 conflicts in R7).
#define ROWSTRIDE 18
#define SLOT_HALVES (162 * ROWSTRIDE)            // 2916
#define TAIL 96                                   // overread zone (rows 162..166 of slot 1)
#define LDS_HALVES (2 * SLOT_HALVES + TAIL)

// R10 = R9 structure, spill fixed: NO min-waves bound (VGPR floats, ~3 waves/SIMD
// naturally). Register-cached A-fragments: each slice gathered from LDS ONCE.
__global__ __launch_bounds__(256) void conv3d_min_softmax_mfma(
    const float* __restrict__ x,
    const float* __restrict__ wgt,
    const float* __restrict__ bias,
    float* __restrict__ out)
{
    __shared__ _Float16 imX[LDS_HALVES];

    const int tid  = threadIdx.x;
    const int wv   = tid >> 6;
    const int lane = tid & 63;
    const int cl   = lane & 15;   // A: px-lane | B/C: co-lane
    const int kg   = lane >> 4;   // A/B: k-group | C: px-row-group
    const bool has11 = (tid < 32);   // elem 10*256+tid < 2592 iff tid < 32

    const int wchunk = blockIdx.x;
    const int band   = blockIdx.y;
    const int b      = blockIdx.z;
    const int w0 = (wchunk < 7) ? wchunk * 16 : 110;   // overlap chunk: identical math, benign
    const int h0 = (band   < 7) ? band   * 16 : 110;

    const float* xb = x + (size_t)b * (CIN * DIN * HW);

    // zero the static tail: slot-1 overreads (k>=27) must see finite data, never NaN
    for (int i = 2 * SLOT_HALVES + tid; i < LDS_HALVES; i += 256)
        imX[i] = (_Float16)0.f;

    // ---- B-fragments (weights) in regs; k-order = kh*9 + ci*3 + kw; pads -> 0
    f16x8 bw[3][2];   // [kd][co-half]
    #pragma unroll
    for (int kd = 0; kd < 3; ++kd)
      #pragma unroll
      for (int hf = 0; hf < 2; ++hf)
        #pragma unroll
        for (int j = 0; j < 8; ++j) {
          int k  = kg * 8 + j;
          int co = hf * 16 + cl;
          float wvv = 0.f;
          if (k < 27 && co < 24) {
            int kh = k / 9, rem = k - kh * 9, ci = rem / 3, kw = rem - ci * 3;
            wvv = wgt[((co * 3 + ci) * 3 + kd) * 9 + kh * 3 + kw];
          }
          bw[kd][hf][j] = (_Float16)wvv;
        }

    const float bias0 = bias[cl];
    const float bias1 = (cl < 8) ? bias[16 + cl] : 0.f;

    // ---- builder offsets: thread handles elems e = tid + it*256, it = 0..10.
    // it < 10 is ALWAYS in range (e < 2560 < 2592); it == 10 valid iff tid < 32.
    int goff[11];   // global offset within a slice
    int lidx[11];   // LDS index within a slot
    #pragma unroll
    for (int it = 0; it < 11; ++it) {
      int e = tid + it * 256;
      int ec = (e < 2592) ? e : 0;
      int hrow = ec / 144, e2 = ec - hrow * 144;
      int ci   = e2 / 48,  e3 = e2 - ci * 48;
      int kw   = e3 >> 4,  px = e3 & 15;
      goff[it] = (ci * DIN) * HW + (h0 + hrow) * WIN + (w0 + kw + px);
      lidx[it] = (hrow * 9 + ci * 3 + kw) * ROWSTRIDE + px;
    }

    // per-tile gather row bases (column cl of rows 9*rel_h+8*kg ..+7)
    int rbase[4];
    #pragma unroll
    for (int t = 0; t < 4; ++t)
      rbase[t] = ((wv * 4 + t) * 9 + kg * 8) * ROWSTRIDE + cl;

    // ---- prologue: build slices 0,1; gather A0,A1; build slice 2; gather A2
    #pragma unroll 1
    for (int s = 0; s < 2; ++s) {
      #pragma unroll
      for (int it = 0; it < 10; ++it)
        imX[s * SLOT_HALVES + lidx[it]] = (_Float16)xb[goff[it] + s * HW];
      if (has11)
        imX[s * SLOT_HALVES + lidx[10]] = (_Float16)xb[goff[10] + s * HW];
    }
    __syncthreads();

    f16x8 A0[4], A1[4], A2[4];
    #pragma unroll
    for (int t = 0; t < 4; ++t)
      #pragma unroll
      for (int j = 0; j < 8; ++j) {
        A0[t][j] = imX[0 * SLOT_HALVES + rbase[t] + j * ROWSTRIDE];
        A1[t][j] = imX[1 * SLOT_HALVES + rbase[t] + j * ROWSTRIDE];
      }
    __syncthreads();   // gathers of slot 0 done before slice-2 overwrite

    #pragma unroll
    for (int it = 0; it < 10; ++it)
      imX[0 * SLOT_HALVES + lidx[it]] = (_Float16)xb[goff[it] + 2 * HW];
    if (has11)
      imX[0 * SLOT_HALVES + lidx[10]] = (_Float16)xb[goff[10] + 2 * HW];
    __syncthreads();

    #pragma unroll
    for (int t = 0; t < 4; ++t)
      #pragma unroll
      for (int j = 0; j < 8; ++j)
        A2[t][j] = imX[0 * SLOT_HALVES + rbase[t] + j * ROWSTRIDE];

    // ---- main dp loop. Invariant entering dp: A0/A1/A2 = slices dp,dp+1,dp+2;
    // slot (dp+1)%2 holds slice dp+1 (disposable), slot dp%2 holds slice dp+2.
    float mn[4][2][4];
    #pragma unroll
    for (int t = 0; t < 4; ++t)
      #pragma unroll
      for (int hf = 0; hf < 2; ++hf)
        #pragma unroll
        for (int j = 0; j < 4; ++j) mn[t][hf][j] = 3.4e38f;

    #pragma unroll 1
    for (int dp = 0; dp < DOUT; ++dp) {
      const bool more = (dp < DOUT - 1);

      // 1) issue next-slice global loads early (hidden under MFMA)
      float stash[11];
      if (more) {
        #pragma unroll
        for (int it = 0; it < 10; ++it)
          stash[it] = xb[goff[it] + (dp + 3) * HW];
        if (has11)
          stash[10] = xb[goff[10] + (dp + 3) * HW];
      }

      // 2) compute from registers: 4 tiles x (3 kd chained) x 2 co-halves
      #pragma unroll
      for (int t = 0; t < 4; ++t) {
        f32x4 z = {0.f, 0.f, 0.f, 0.f};
        f32x4 acc0 = __builtin_amdgcn_mfma_f32_16x16x32_f16(A0[t], bw[0][0], z, 0, 0, 0);
        f32x4 acc1 = __builtin_amdgcn_mfma_f32_16x16x32_f16(A0[t], bw[0][1], z, 0, 0, 0);
        acc0 = __builtin_amdgcn_mfma_f32_16x16x32_f16(A1[t], bw[1][0], acc0, 0, 0, 0);
        acc1 = __builtin_amdgcn_mfma_f32_16x16x32_f16(A1[t], bw[1][1], acc1, 0, 0, 0);
        acc0 = __builtin_amdgcn_mfma_f32_16x16x32_f16(A2[t], bw[2][0], acc0, 0, 0, 0);
        acc1 = __builtin_amdgcn_mfma_f32_16x16x32_f16(A2[t], bw[2][1], acc1, 0, 0, 0);
        #pragma unroll
        for (int j = 0; j < 4; ++j) {
          mn[t][0][j] = fminf(mn[t][0][j], acc0[j]);
          mn[t][1][j] = fminf(mn[t][1][j], acc1[j]);
        }
      }

      if (more) {
        // 3) write slice dp+3 into slot (dp+1)%2 (slice dp+1's LDS copy is dead)
        const int sb = ((dp + 1) & 1) * SLOT_HALVES;
        #pragma unroll
        for (int it = 0; it < 10; ++it)
          imX[sb + lidx[it]] = (_Float16)stash[it];
        if (has11)
          imX[sb + lidx[10]] = (_Float16)stash[10];
        // 4) barrier, then 5) shift regs + gather slice dp+3 once
        __syncthreads();
        #pragma unroll
        for (int t = 0; t < 4; ++t) { A0[t] = A1[t]; A1[t] = A2[t]; }
        #pragma unroll
        for (int t = 0; t < 4; ++t)
          #pragma unroll
          for (int j = 0; j < 8; ++j)
            A2[t][j] = imX[sb + rbase[t] + j * ROWSTRIDE];
      }
    }

    // ---- fused bias + softmax over channels (cross-lane over 16-lane group)
    float* ob = out + (size_t)b * COUT * HOUT * HOUT;
    #pragma unroll
    for (int t = 0; t < 4; ++t) {
      const int h = h0 + wv * 4 + t;
      #pragma unroll
      for (int j = 0; j < 4; ++j) {
        float v0 = mn[t][0][j] + bias0;
        float v1 = (cl < 8) ? (mn[t][1][j] + bias1) : -3.4e38f;
        float mx = fmaxf(v0, v1);
        #pragma unroll
        for (int msk = 1; msk < 16; msk <<= 1)
          mx = fmaxf(mx, __shfl_xor(mx, msk));
        float e0 = __expf(v0 - mx);
        float e1 = (cl < 8) ? __expf(v1 - mx) : 0.f;
        float sm = e0 + e1;
        #pragma unroll
        for (int msk = 1; msk < 16; msk <<= 1)
          sm += __shfl_xor(sm, msk);
        float r = 1.f / sm;
        const int w = w0 + kg * 4 + j;
        ob[((size_t)cl * HOUT + h) * HOUT + w] = e0 * r;
        if (cl < 8)
          ob[((size_t)(16 + cl) * HOUT + h) * HOUT + w] = e1 * r;
      }
    }
}

extern "C" void kernel_launch(void* const* d_in, const int* in_sizes, int n_in,
                              void* d_out, int out_size, void* d_ws, size_t ws_size,
                              hipStream_t stream) {
    const float* x    = (const float*)d_in[0];
    const float* wgt  = (const float*)d_in[1];
    const float* bias = (const float*)d_in[2];
    float* out        = (float*)d_out;

    dim3 grid(8, 8, 16);   // (wchunk, band, b)
    dim3 block(256);
    conv3d_min_softmax_mfma<<<grid, block, 0, stream>>>(x, wgt, bias, out);
}